// Round 1
// baseline (188.101 us; speedup 1.0000x reference)
//
#include <hip/hip_runtime.h>
#include <math.h>

#define M_CLUSTERS 64
#define D_DIM 128
#define BLOCK 256

// Kernel 1: m2[m] = sum_d mus[m][d]^2  (64 values into d_ws)
__global__ void iso_m2_kernel(const float* __restrict__ mus, float* __restrict__ m2) {
    int m = threadIdx.x;
    if (m < M_CLUSTERS) {
        const float4* mv = reinterpret_cast<const float4*>(mus) + m * (D_DIM / 4);
        float s = 0.f;
#pragma unroll
        for (int d = 0; d < D_DIM / 4; ++d) {
            float4 v = mv[d];
            s = fmaf(v.x, v.x, s);
            s = fmaf(v.y, v.y, s);
            s = fmaf(v.z, v.z, s);
            s = fmaf(v.w, v.w, s);
        }
        m2[m] = s;
    }
}

// Kernel 2: one thread per row n. acc[m] = X[n]·mus[m] for all 64 m,
// then epilogue + r-weighted row sum, block-reduced into partials[block].
__global__ __launch_bounds__(BLOCK) void iso_main_kernel(
        const float* __restrict__ X, const float* __restrict__ r,
        const float* __restrict__ mus, const float* __restrict__ m2,
        float* __restrict__ partials, int N) {
    const int n = blockIdx.x * BLOCK + threadIdx.x;
    float rowsum = 0.f;
    if (n < N) {
        const float4* Xv = reinterpret_cast<const float4*>(X) + (size_t)n * (D_DIM / 4);
        const float4* Mv = reinterpret_cast<const float4*>(mus);  // wave-uniform -> s_load
        float acc[M_CLUSTERS];
#pragma unroll
        for (int m = 0; m < M_CLUSTERS; ++m) acc[m] = 0.f;
        float x2 = 0.f;
#pragma unroll 1
        for (int d = 0; d < D_DIM / 4; ++d) {
            float4 x = Xv[d];
            x2 = fmaf(x.x, x.x, x2);
            x2 = fmaf(x.y, x.y, x2);
            x2 = fmaf(x.z, x.z, x2);
            x2 = fmaf(x.w, x.w, x2);
#pragma unroll
            for (int m = 0; m < M_CLUSTERS; ++m) {
                float4 mu = Mv[m * (D_DIM / 4) + d];
                acc[m] = fmaf(x.x, mu.x, acc[m]);
                acc[m] = fmaf(x.y, mu.y, acc[m]);
                acc[m] = fmaf(x.z, mu.z, acc[m]);
                acc[m] = fmaf(x.w, mu.w, acc[m]);
            }
        }
        const float4* Rv = reinterpret_cast<const float4*>(r) + (size_t)n * (M_CLUSTERS / 4);
#pragma unroll
        for (int q = 0; q < M_CLUSTERS / 4; ++q) {
            float4 rv = Rv[q];
            float v[4];
#pragma unroll
            for (int j = 0; j < 4; ++j) {
                int m = q * 4 + j;
                float sq = x2 + m2[m] - 2.0f * acc[m];
                float dd = sqrtf(fmaxf(sq, 0.f));
                // sigmoid(-dd) = 1/(1+exp(dd)); sim_z = -log(sigmoid + 1e-8)
                float sg = __fdividef(1.0f, 1.0f + __expf(dd));
                v[j] = -__logf(sg + 1e-8f);
            }
            rowsum = fmaf(rv.x, v[0], rowsum);
            rowsum = fmaf(rv.y, v[1], rowsum);
            rowsum = fmaf(rv.z, v[2], rowsum);
            rowsum = fmaf(rv.w, v[3], rowsum);
        }
    }
    // block reduce (wave64 shuffle, then LDS across 4 waves)
#pragma unroll
    for (int off = 32; off > 0; off >>= 1)
        rowsum += __shfl_down(rowsum, off, 64);
    __shared__ float wsum[BLOCK / 64];
    const int lane = threadIdx.x & 63;
    const int wid = threadIdx.x >> 6;
    if (lane == 0) wsum[wid] = rowsum;
    __syncthreads();
    if (threadIdx.x == 0)
        partials[blockIdx.x] = wsum[0] + wsum[1] + wsum[2] + wsum[3];
}

// Kernel 3: deterministic fixed-order final reduction, writes loss/N.
__global__ void iso_reduce_kernel(const float* __restrict__ partials, int nblocks,
                                  float* __restrict__ out, float invN) {
    float s = 0.f;
    for (int i = threadIdx.x; i < nblocks; i += BLOCK) s += partials[i];
#pragma unroll
    for (int off = 32; off > 0; off >>= 1)
        s += __shfl_down(s, off, 64);
    __shared__ float wsum[BLOCK / 64];
    const int lane = threadIdx.x & 63;
    const int wid = threadIdx.x >> 6;
    if (lane == 0) wsum[wid] = s;
    __syncthreads();
    if (threadIdx.x == 0)
        out[0] = (wsum[0] + wsum[1] + wsum[2] + wsum[3]) * invN;
}

extern "C" void kernel_launch(void* const* d_in, const int* in_sizes, int n_in,
                              void* d_out, int out_size, void* d_ws, size_t ws_size,
                              hipStream_t stream) {
    const float* X = (const float*)d_in[0];    // [N,128]
    const float* r = (const float*)d_in[1];    // [N,64]
    const float* mus = (const float*)d_in[2];  // [64,128]
    const int N = in_sizes[0] / D_DIM;

    float* m2 = (float*)d_ws;           // 64 floats
    float* partials = m2 + M_CLUSTERS;  // nblocks floats

    const int nblocks = (N + BLOCK - 1) / BLOCK;

    hipLaunchKernelGGL(iso_m2_kernel, dim3(1), dim3(64), 0, stream, mus, m2);
    hipLaunchKernelGGL(iso_main_kernel, dim3(nblocks), dim3(BLOCK), 0, stream,
                       X, r, mus, m2, partials, N);
    hipLaunchKernelGGL(iso_reduce_kernel, dim3(1), dim3(BLOCK), 0, stream,
                       partials, nblocks, (float*)d_out, 1.0f / (float)N);
}

// Round 2
// 101.321 us; speedup vs baseline: 1.8565x; 1.8565x over previous
//
#include <hip/hip_runtime.h>
#include <math.h>

#define D_DIM 128
#define D4 32            // 128/4 float4s per row
#define M_CLUSTERS 64
#define MPW 16           // clusters per wave
#define ROWS 64          // rows per block
#define BLOCK 256
#define RBLOCK 256

// Prep: muR[(w*32+d4)*16+mm] = float4 mus[w*16+mm][d4*4..+3]  (per-wave contiguous
// so the main kernel's scalar loads stream 256B/d-iter), plus m2[m] = ||mu_m||^2.
__global__ void iso_prep(const float4* __restrict__ mus, float4* __restrict__ muR,
                         float* __restrict__ m2) {
    const int t = threadIdx.x;
#pragma unroll
    for (int i = 0; i < 8; ++i) {
        int f = i * 256 + t;          // 0..2047
        int w = f >> 9;               // /(32*16)
        int d4 = (f >> 4) & 31;
        int mm = f & 15;
        muR[f] = mus[(w * MPW + mm) * D4 + d4];
    }
    if (t < M_CLUSTERS) {
        float s = 0.f;
#pragma unroll
        for (int d = 0; d < D4; ++d) {
            float4 v = mus[t * D4 + d];
            s = fmaf(v.x, v.x, s);
            s = fmaf(v.y, v.y, s);
            s = fmaf(v.z, v.z, s);
            s = fmaf(v.w, v.w, s);
        }
        m2[t] = s;
    }
}

__device__ __forceinline__ float zval(float x2, float m2v, float a) {
    float sq = x2 + m2v - 2.0f * a;
    float dd = sqrtf(fmaxf(sq, 0.0f));
    float sg = __fdividef(1.0f, 1.0f + __expf(dd));
    return -__logf(sg + 1e-8f);
}

// Main: block = 4 waves x 64 lanes. Block owns 64 rows (lane = row), wave w owns
// clusters [w*16, w*16+16). X tile staged in LDS (XOR-swizzled, T2 pattern);
// mus fragments come via wave-uniform s_loads from muR.
__global__ __launch_bounds__(BLOCK) void iso_main(
        const float4* __restrict__ X, const float* __restrict__ r,
        const float4* __restrict__ muR, const float* __restrict__ m2,
        float* __restrict__ partials, int N) {
    __shared__ float4 xt[ROWS * D4];   // 32 KB
    const int tid = threadIdx.x;
    const int lane = tid & 63;
    const int wu = __builtin_amdgcn_readfirstlane(tid >> 6);  // force SGPR path
    const int rowbase = blockIdx.x * ROWS;

    // Stage X tile: 2048 float4s, coalesced; swizzle col ^= (row & 7) (T2/G4).
#pragma unroll
    for (int i = 0; i < 8; ++i) {
        int f = i * 256 + tid;
        int rr = f >> 5;
        int cc = f & 31;
        float4 v = make_float4(0.f, 0.f, 0.f, 0.f);
        if (rowbase + rr < N) v = X[(size_t)(rowbase + rr) * D4 + cc];
        xt[(rr << 5) | (cc ^ (rr & 7))] = v;
    }
    __syncthreads();

    float acc[MPW];
#pragma unroll
    for (int mm = 0; mm < MPW; ++mm) acc[mm] = 0.f;
    float x2 = 0.f;

    const float4* mw = muR + wu * (D4 * MPW);  // uniform base
    const int xbase = lane << 5;
    const int xswz = lane & 7;

#pragma unroll 4
    for (int d4 = 0; d4 < D4; ++d4) {
        float4 x = xt[xbase | (d4 ^ xswz)];
        x2 = fmaf(x.x, x.x, x2);
        x2 = fmaf(x.y, x.y, x2);
        x2 = fmaf(x.z, x.z, x2);
        x2 = fmaf(x.w, x.w, x2);
        const float4* mc = mw + d4 * MPW;      // uniform -> s_load_dwordx16 stream
#pragma unroll
        for (int mm = 0; mm < MPW; ++mm) {
            float4 mu = mc[mm];
            acc[mm] = fmaf(x.x, mu.x, acc[mm]);
            acc[mm] = fmaf(x.y, mu.y, acc[mm]);
            acc[mm] = fmaf(x.z, mu.z, acc[mm]);
            acc[mm] = fmaf(x.w, mu.w, acc[mm]);
        }
    }

    // Epilogue: distances -> sim_z -> r-weighted partial for (row=lane, wave wu).
    const int row = rowbase + lane;
    float partial = 0.f;
    if (row < N) {
        const float4* rv = reinterpret_cast<const float4*>(r) +
                           (size_t)row * (M_CLUSTERS / 4) + wu * 4;
        const float* m2w = m2 + wu * MPW;
#pragma unroll
        for (int q = 0; q < 4; ++q) {
            float4 rq = rv[q];
            partial = fmaf(rq.x, zval(x2, m2w[q * 4 + 0], acc[q * 4 + 0]), partial);
            partial = fmaf(rq.y, zval(x2, m2w[q * 4 + 1], acc[q * 4 + 1]), partial);
            partial = fmaf(rq.z, zval(x2, m2w[q * 4 + 2], acc[q * 4 + 2]), partial);
            partial = fmaf(rq.w, zval(x2, m2w[q * 4 + 3], acc[q * 4 + 3]), partial);
        }
    }

    // Block reduce: reuse xt LDS (barrier first). part[w*64+lane] -> wave 0 sums.
    __syncthreads();
    float* pl = reinterpret_cast<float*>(xt);
    pl[(tid >> 6) * 64 + lane] = partial;
    __syncthreads();
    if (tid < 64) {
        float s = pl[lane] + pl[64 + lane] + pl[128 + lane] + pl[192 + lane];
#pragma unroll
        for (int off = 32; off > 0; off >>= 1)
            s += __shfl_down(s, off, 64);
        if (lane == 0) partials[blockIdx.x] = s;
    }
}

// Deterministic fixed-order final reduction.
__global__ void iso_reduce(const float* __restrict__ partials, int nblocks,
                           float* __restrict__ out, float invN) {
    float s = 0.f;
    for (int i = threadIdx.x; i < nblocks; i += RBLOCK) s += partials[i];
#pragma unroll
    for (int off = 32; off > 0; off >>= 1)
        s += __shfl_down(s, off, 64);
    __shared__ float wsum[RBLOCK / 64];
    const int lane = threadIdx.x & 63;
    const int wid = threadIdx.x >> 6;
    if (lane == 0) wsum[wid] = s;
    __syncthreads();
    if (threadIdx.x == 0)
        out[0] = (wsum[0] + wsum[1] + wsum[2] + wsum[3]) * invN;
}

extern "C" void kernel_launch(void* const* d_in, const int* in_sizes, int n_in,
                              void* d_out, int out_size, void* d_ws, size_t ws_size,
                              hipStream_t stream) {
    const float* X = (const float*)d_in[0];    // [N,128]
    const float* r = (const float*)d_in[1];    // [N,64]
    const float* mus = (const float*)d_in[2];  // [64,128]
    const int N = in_sizes[0] / D_DIM;

    // ws layout (16B-aligned): muR (2048 float4 = 32KB) | m2 (64 f) | partials
    float4* muR = (float4*)d_ws;
    float* m2 = (float*)d_ws + 2048 * 4;
    float* partials = m2 + 64;

    const int nblocks = (N + ROWS - 1) / ROWS;

    hipLaunchKernelGGL(iso_prep, dim3(1), dim3(256), 0, stream,
                       (const float4*)mus, muR, m2);
    hipLaunchKernelGGL(iso_main, dim3(nblocks), dim3(BLOCK), 0, stream,
                       (const float4*)X, r, muR, m2, partials, N);
    hipLaunchKernelGGL(iso_reduce, dim3(1), dim3(RBLOCK), 0, stream,
                       partials, nblocks, (float*)d_out, 1.0f / (float)N);
}

// Round 3
// 48.545 us; speedup vs baseline: 3.8748x; 2.0871x over previous
//
#include <hip/hip_runtime.h>
#include <math.h>

#define D_DIM 128
#define M_CLUSTERS 64
#define ROWS 128          // rows per block (4 waves x 32 rows)
#define BLOCK 256
#define RBLOCK 256

typedef __bf16 bf16x8 __attribute__((ext_vector_type(8)));
typedef float f32x4 __attribute__((ext_vector_type(4)));

union B8 {
    int4 i;
    bf16x8 b;
    unsigned int u[4];
};

__device__ __forceinline__ unsigned int pack_bf16(float a, float b) {
    unsigned int ua = __float_as_uint(a), ub = __float_as_uint(b);
    ua = (ua + 0x7FFFu + ((ua >> 16) & 1u)) >> 16;   // RN-even
    ub = (ub + 0x7FFFu + ((ub >> 16) & 1u)) >> 16;
    return ua | (ub << 16);
}

__device__ __forceinline__ float zval(float sq) {
    float dd = sqrtf(fmaxf(sq, 0.0f));
    float sg = __fdividef(1.0f, 1.0f + __expf(dd));
    return -__logf(sg + 1e-8f);
}

// Prep: muB = bf16(mus) linear [64][128]; m2[m] = ||mu_m||^2 in f32.
__global__ void iso_prep(const float4* __restrict__ mus4, int4* __restrict__ muB4,
                         float* __restrict__ m2) {
    const int t = threadIdx.x;
#pragma unroll
    for (int i = 0; i < 4; ++i) {
        int f = i * 256 + t;               // 1024 chunks of 8 f32
        float4 v0 = mus4[f * 2 + 0];
        float4 v1 = mus4[f * 2 + 1];
        int4 p;
        p.x = (int)pack_bf16(v0.x, v0.y);
        p.y = (int)pack_bf16(v0.z, v0.w);
        p.z = (int)pack_bf16(v1.x, v1.y);
        p.w = (int)pack_bf16(v1.z, v1.w);
        muB4[f] = p;
    }
    if (t < M_CLUSTERS) {
        const float4* mv = mus4 + t * (D_DIM / 4);
        float s = 0.f;
#pragma unroll
        for (int d = 0; d < D_DIM / 4; ++d) {
            float4 v = mv[d];
            s = fmaf(v.x, v.x, s);
            s = fmaf(v.y, v.y, s);
            s = fmaf(v.z, v.z, s);
            s = fmaf(v.w, v.w, s);
        }
        m2[t] = s;
    }
}

// Main: S = X_bf16 @ mus_bf16^T per 128-row tile via MFMA, fused epilogue.
__global__ __launch_bounds__(BLOCK) void iso_main(
        const float4* __restrict__ X4, const float* __restrict__ r,
        const int4* __restrict__ muB4, const float* __restrict__ m2g,
        float* __restrict__ partials, int N) {
    // LDS: xs = X tile bf16 [128 rows][16 x 16B slots], swizzled slot^ (row&7)
    //      bs = mus bf16 [64][16 slots], same swizzle. x2s, pl for reductions.
    __shared__ int4 xs[ROWS * 16];        // 32 KB
    __shared__ int4 bs[M_CLUSTERS * 16];  // 16 KB
    __shared__ float x2s[ROWS];
    __shared__ float pl[BLOCK];

    const int tid = threadIdx.x;
    const int lane = tid & 63;
    const int w = tid >> 6;
    const int la = lane & 15;
    const int lg = lane >> 4;
    const int rowbase = blockIdx.x * ROWS;

    // Stage X (convert f32->bf16): 2048 chunks of 8 f32, coalesced 32B/lane.
#pragma unroll
    for (int i = 0; i < 8; ++i) {
        int f = i * 256 + tid;
        int row = f >> 4, c8 = f & 15;
        int4 p = make_int4(0, 0, 0, 0);
        if (rowbase + row < N) {
            const float4* xv = X4 + (size_t)(rowbase + row) * 32 + c8 * 2;
            float4 v0 = xv[0], v1 = xv[1];
            p.x = (int)pack_bf16(v0.x, v0.y);
            p.y = (int)pack_bf16(v0.z, v0.w);
            p.z = (int)pack_bf16(v1.x, v1.y);
            p.w = (int)pack_bf16(v1.z, v1.w);
        }
        xs[row * 16 + (c8 ^ (row & 7))] = p;
    }
    // Stage mus (already bf16 in ws): 1024 chunks.
#pragma unroll
    for (int i = 0; i < 4; ++i) {
        int f = i * 256 + tid;
        int c = f >> 4, c16 = f & 15;
        bs[c * 16 + (c16 ^ (c & 7))] = muB4[f];
    }
    __syncthreads();

    // K-loop: wave w owns rows [w*32, w*32+32). acc[ra][cb]: 2x4 16x16 tiles.
    f32x4 acc[2][4];
#pragma unroll
    for (int ra = 0; ra < 2; ++ra)
#pragma unroll
        for (int cb = 0; cb < 4; ++cb)
#pragma unroll
            for (int q = 0; q < 4; ++q) acc[ra][cb][q] = 0.f;
    float x2p[2] = {0.f, 0.f};

#pragma unroll
    for (int kk = 0; kk < 4; ++kk) {
        const int slot = kk * 4 + lg;
        B8 a[2];
#pragma unroll
        for (int ra = 0; ra < 2; ++ra) {
            int row = w * 32 + ra * 16 + la;
            a[ra].i = xs[row * 16 + (slot ^ (row & 7))];
        }
        B8 b[4];
#pragma unroll
        for (int cb = 0; cb < 4; ++cb) {
            int c = cb * 16 + la;
            b[cb].i = bs[c * 16 + (slot ^ (c & 7))];
        }
#pragma unroll
        for (int ra = 0; ra < 2; ++ra)
#pragma unroll
            for (int cb = 0; cb < 4; ++cb)
                acc[ra][cb] = __builtin_amdgcn_mfma_f32_16x16x32_bf16(
                    a[ra].b, b[cb].b, acc[ra][cb], 0, 0, 0);
        // x2 from the same bf16 A-fragments (exact bf16->f32 via bit shift)
#pragma unroll
        for (int ra = 0; ra < 2; ++ra)
#pragma unroll
            for (int j = 0; j < 4; ++j) {
                unsigned int u = a[ra].u[j];
                float f0 = __uint_as_float(u << 16);
                float f1 = __uint_as_float(u & 0xFFFF0000u);
                x2p[ra] = fmaf(f0, f0, fmaf(f1, f1, x2p[ra]));
            }
    }

    // Each lane has 1/4 of its row's x2 -> xor-reduce over lane groups.
#pragma unroll
    for (int ra = 0; ra < 2; ++ra) {
        x2p[ra] += __shfl_xor(x2p[ra], 16, 64);
        x2p[ra] += __shfl_xor(x2p[ra], 32, 64);
    }
    if (lg == 0) {
        x2s[w * 32 + 0 * 16 + la] = x2p[0];
        x2s[w * 32 + 1 * 16 + la] = x2p[1];
    }
    // same-wave LDS write->read; compiler orders via lgkmcnt (no barrier needed)

    // Epilogue. C/D layout (m89): col = lane&15, row = (lane>>4)*4 + q.
    float m2r[4];
#pragma unroll
    for (int cb = 0; cb < 4; ++cb) m2r[cb] = m2g[cb * 16 + la];
    float x2r[2][4];
#pragma unroll
    for (int ra = 0; ra < 2; ++ra)
#pragma unroll
        for (int q = 0; q < 4; ++q)
            x2r[ra][q] = x2s[w * 32 + ra * 16 + lg * 4 + q];

    float partial = 0.f;
#pragma unroll
    for (int ra = 0; ra < 2; ++ra)
#pragma unroll
        for (int q = 0; q < 4; ++q) {
            int grow = rowbase + w * 32 + ra * 16 + lg * 4 + q;
            if (grow < N) {
                const float* rrow = r + (size_t)grow * M_CLUSTERS;
#pragma unroll
                for (int cb = 0; cb < 4; ++cb) {
                    float rv = rrow[cb * 16 + la];
                    float sq = x2r[ra][q] + m2r[cb] - 2.0f * acc[ra][cb][q];
                    partial = fmaf(rv, zval(sq), partial);
                }
            }
        }

    // Block reduce.
    pl[tid] = partial;
    __syncthreads();
    if (tid < 64) {
        float s = pl[lane] + pl[64 + lane] + pl[128 + lane] + pl[192 + lane];
#pragma unroll
        for (int off = 32; off > 0; off >>= 1)
            s += __shfl_down(s, off, 64);
        if (lane == 0) partials[blockIdx.x] = s;
    }
}

// Deterministic fixed-order final reduction.
__global__ void iso_reduce(const float* __restrict__ partials, int nblocks,
                           float* __restrict__ out, float invN) {
    float s = 0.f;
    for (int i = threadIdx.x; i < nblocks; i += RBLOCK) s += partials[i];
#pragma unroll
    for (int off = 32; off > 0; off >>= 1)
        s += __shfl_down(s, off, 64);
    __shared__ float wsum[RBLOCK / 64];
    const int lane = threadIdx.x & 63;
    const int wid = threadIdx.x >> 6;
    if (lane == 0) wsum[wid] = s;
    __syncthreads();
    if (threadIdx.x == 0)
        out[0] = (wsum[0] + wsum[1] + wsum[2] + wsum[3]) * invN;
}

extern "C" void kernel_launch(void* const* d_in, const int* in_sizes, int n_in,
                              void* d_out, int out_size, void* d_ws, size_t ws_size,
                              hipStream_t stream) {
    const float* X = (const float*)d_in[0];    // [N,128]
    const float* r = (const float*)d_in[1];    // [N,64]
    const float* mus = (const float*)d_in[2];  // [64,128]
    const int N = in_sizes[0] / D_DIM;

    // ws: muB4 (1024 int4 = 16KB) | m2 (64 f32) | partials (nblocks f32)
    int4* muB4 = (int4*)d_ws;
    float* m2 = (float*)((char*)d_ws + 16384);
    float* partials = m2 + M_CLUSTERS;

    const int nblocks = (N + ROWS - 1) / ROWS;

    hipLaunchKernelGGL(iso_prep, dim3(1), dim3(256), 0, stream,
                       (const float4*)mus, muB4, m2);
    hipLaunchKernelGGL(iso_main, dim3(nblocks), dim3(BLOCK), 0, stream,
                       (const float4*)X, r, muB4, m2, partials, N);
    hipLaunchKernelGGL(iso_reduce, dim3(1), dim3(RBLOCK), 0, stream,
                       partials, nblocks, (float*)d_out, 1.0f / (float)N);
}